// Round 1
// baseline (23100.552 us; speedup 1.0000x reference)
//
#include <hip/hip_runtime.h>

// ============================================================================
// 2-layer LSTM (B=64,T=512,D=256,H=1024) + linear, fp32.
// Persistent-kernel design:
//  - 256 WGs x 128 thr, ~139KB LDS each => guaranteed 1 WG/CU, all co-resident
//    => custom grid barrier is safe without cooperative launch.
//  - Diagonal pipeline: phase p = layer0 step p  ||  layer1 step p-1. 513 barriers.
//  - Weights quantized to int16 (scale 2^19), split into two int8 planes
//    (hi*256+lo), persistent in LDS. Activations int16 (x: 2^11, h: 2^14),
//    split on the fly into hi/lo int8 via v_perm. 3x mfma_i32_32x32x32_i8
//    per K=32 gives ~fp32-accurate gates (error ~1e-4 on gates, ~2e-5 final).
//  - Gate rows reordered so col 4j+g = gate g of hidden unit j => each WG owns
//    complete units; c-state lives in LDS; h broadcast via ping-pong i16 bufs.
// ============================================================================

#define T_STEPS 512
#define NWG 256
#define LDS_W     131072                  // [64 ksteps][2 planes][64 lanes][16B]
#define LDS_GBUF  (64 * 33 * 4)           // 8448, padded stride 33
#define LDS_CBUF  (64 * 9 * 4)            // 2304, padded stride 9
#define LDS_OFFS  (32 * 4)
#define SMEM_BYTES (LDS_W + LDS_GBUF + LDS_CBUF + LDS_OFFS)   // 141952

typedef int v4i  __attribute__((ext_vector_type(4)));
typedef int v16i __attribute__((ext_vector_type(16)));

__device__ __forceinline__ v16i zero16() {
    v16i z;
#pragma unroll
    for (int i = 0; i < 16; ++i) z[i] = 0;
    return z;
}

// One K=32 step: load 16 i16 activations (32B), split into hi/lo i8 planes,
// read B hi/lo frags from LDS, 3 int8 MFMAs (hh into acc_hh, cross into acc_mid).
__device__ __forceinline__ void kstep(const short* __restrict__ ap,
                                      const char* __restrict__ wl,
                                      v16i& ahh, v16i& amid)
{
    v4i A0 = *(const v4i*)ap;          // k0..k7  (8 x i16)
    v4i A1 = *(const v4i*)(ap + 8);    // k8..k15
    v4i HI, LO;
    HI.x = (int)__builtin_amdgcn_perm((unsigned)A0.y, (unsigned)A0.x, 0x07050301u);
    HI.y = (int)__builtin_amdgcn_perm((unsigned)A0.w, (unsigned)A0.z, 0x07050301u);
    HI.z = (int)__builtin_amdgcn_perm((unsigned)A1.y, (unsigned)A1.x, 0x07050301u);
    HI.w = (int)__builtin_amdgcn_perm((unsigned)A1.w, (unsigned)A1.z, 0x07050301u);
    // low byte, biased to signed: LO' = LO_u - 128  (bit pattern = byte ^ 0x80)
    LO.x = (int)(__builtin_amdgcn_perm((unsigned)A0.y, (unsigned)A0.x, 0x06040200u) ^ 0x80808080u);
    LO.y = (int)(__builtin_amdgcn_perm((unsigned)A0.w, (unsigned)A0.z, 0x06040200u) ^ 0x80808080u);
    LO.z = (int)(__builtin_amdgcn_perm((unsigned)A1.y, (unsigned)A1.x, 0x06040200u) ^ 0x80808080u);
    LO.w = (int)(__builtin_amdgcn_perm((unsigned)A1.w, (unsigned)A1.z, 0x06040200u) ^ 0x80808080u);
    v4i BH = *(const v4i*)wl;
    v4i BL = *(const v4i*)(wl + 1024);
    ahh  = __builtin_amdgcn_mfma_i32_32x32x32_i8(HI, BH, ahh, 0, 0, 0);
    amid = __builtin_amdgcn_mfma_i32_32x32x32_i8(HI, BL, amid, 0, 0, 0);
    amid = __builtin_amdgcn_mfma_i32_32x32x32_i8(LO, BH, amid, 0, 0, 0);
}

// ---------------------------------------------------------------------------
// prep: quantize x to i16 (scale 2^11)
__global__ void quant_x(const float* __restrict__ x, short* __restrict__ xq, int n)
{
    int i = blockIdx.x * 256 + threadIdx.x;
    if (i < n) {
        float v = x[i] * 2048.f;
        v = fminf(fmaxf(v, -32767.f), 32767.f);
        xq[i] = (short)__float2int_rn(v);
    }
}

// prep: quantize + gate-reorder + fragment-tile weights into per-WG LDS images.
// img[wg][s<64][plane<2][lane<64][16B]; col = (wg&127)*32 + (lane&31) in
// reordered space (row' 4j+g <- orig row g*1024+j); k = s*32 + (lane>>5)*16 + j.
__global__ void quant_w(const float* __restrict__ wih0, const float* __restrict__ whh0,
                        const float* __restrict__ wih1, const float* __restrict__ whh1,
                        char* __restrict__ wimg)
{
    int gid = blockIdx.x * 256 + threadIdx.x;       // 256*64*64 = 1048576 threads
    if (gid >= 256 * 64 * 64) return;
    int lane = gid & 63;
    int s    = (gid >> 6) & 63;
    int wg   = gid >> 12;
    int layer = wg >> 7, nblk = wg & 127;
    int col = nblk * 32 + (lane & 31);
    int ro  = (col & 3) * 1024 + (col >> 2);        // original gate-blocked row
    int k0  = s * 32 + (lane >> 5) * 16;
    char* dst = wimg + (size_t)wg * LDS_W + s * 2048 + lane * 16;
#pragma unroll
    for (int j = 0; j < 16; ++j) {
        int k = k0 + j;
        float w = 0.f;
        if (layer == 0) {
            if (k < 256)       w = wih0[ro * 256 + k];
            else if (k < 1280) w = whh0[ro * 1024 + (k - 256)];
        } else {
            if (k < 1024)      w = wih1[ro * 1024 + k];
            else               w = whh1[ro * 1024 + (k - 1024)];
        }
        int q  = __float2int_rn(w * 524288.f);      // 2^19, |q|<=16384
        int hi = (q + 128) >> 8;
        int lo = q - (hi << 8);
        dst[j]        = (char)hi;
        dst[1024 + j] = (char)lo;
    }
}

// ---------------------------------------------------------------------------
__global__ void __launch_bounds__(128) lstm_main(
    const short* __restrict__ xq, const char* __restrict__ wimg,
    const float* __restrict__ bih0, const float* __restrict__ bhh0,
    const float* __restrict__ bih1, const float* __restrict__ bhh1,
    short* __restrict__ h0q, short* __restrict__ h2q,
    float* __restrict__ h2f, unsigned* barcnt, unsigned* bargen)
{
    extern __shared__ char smem[];
    char*  wlds = smem;
    float* gbuf = (float*)(smem + LDS_W);                       // [64][33]
    float* cbuf = (float*)(smem + LDS_W + LDS_GBUF);            // [64][9]
    float* offs = (float*)(smem + LDS_W + LDS_GBUF + LDS_CBUF); // [32]

    const int wg    = blockIdx.x;
    const int layer = wg >> 7;
    const int nblk  = wg & 127;
    const int tid   = threadIdx.x;
    const int lane  = tid & 63;

    // stage this WG's weight image into LDS (128KB)
    {
        const v4i* src = (const v4i*)(wimg + (size_t)wg * LDS_W);
        v4i* dst = (v4i*)wlds;
        for (int i = tid; i < LDS_W / 16; i += 128) dst[i] = src[i];
    }
    for (int i = tid; i < 64 * 9; i += 128) cbuf[i] = 0.f;
    __syncthreads();

    // per-col constant: 128*colsum16*inv_scale (the LO'=-128 bias compensation)
    // + combined gate bias, computed from LDS weights.
    if (tid < 32) {
        const int c  = tid;
        const int ns = (layer == 0) ? 40 : 64;
        int cs_x = 0, cs_h = 0;
        for (int s = 0; s < ns; ++s) {
            int sum = 0;
#pragma unroll
            for (int half = 0; half < 2; ++half) {
                const signed char* ph = (const signed char*)(wlds + s * 2048 + (half * 32 + c) * 16);
#pragma unroll
                for (int j = 0; j < 16; ++j)
                    sum += 256 * (int)ph[j] + (int)ph[1024 + j];
            }
            if (layer == 0 && s < 8) cs_x += sum; else cs_h += sum;
        }
        const int col = nblk * 32 + c;
        const int ro  = (col & 3) * 1024 + (col >> 2);
        const float bias = (layer == 0) ? (bih0[ro] + bhh0[ro]) : (bih1[ro] + bhh1[ro]);
        float off = 128.f * (float)cs_h * (1.f / 8589934592.f) + bias;   // /2^33
        if (layer == 0) off += 128.f * (float)cs_x * (1.f / 1073741824.f); // /2^30
        offs[c] = off;
    }
    __syncthreads();

    const int mrow = (tid >> 6) * 32 + (lane & 31);   // batch row of A fragment
    const int ksub = (lane >> 5) * 16;                // k sub-offset (i16 units)

    for (int p = 0; p <= T_STEPS; ++p) {
        const bool active = (layer == 0) ? (p < T_STEPS) : (p >= 1);
        if (active) {
            const short* hprev = h0q + ((p + 1) & 1) * 65536 + mrow * 1024 + ksub; // h0(p-1)
            float gates[16];
            v16i ahh = zero16(), amid = zero16();
            if (layer == 0) {
                // x segment (K=256, scale 2^11 * 2^19 = 2^30)
                const short* ax = xq + ((size_t)mrow * 512 + p) * 256 + ksub;
#pragma unroll
                for (int s = 0; s < 8; ++s)
                    kstep(ax + s * 32, wlds + s * 2048 + lane * 16, ahh, amid);
                float px[16];
#pragma unroll
                for (int r = 0; r < 16; ++r)
                    px[r] = ((float)ahh[r] * 65536.f + (float)amid[r] * 256.f) * (1.f / 1073741824.f);
                ahh = zero16(); amid = zero16();
                // h segment (K=1024, scale 2^14 * 2^19 = 2^33)
#pragma unroll 4
                for (int s = 0; s < 32; ++s)
                    kstep(hprev + s * 32, wlds + (8 + s) * 2048 + lane * 16, ahh, amid);
#pragma unroll
                for (int r = 0; r < 16; ++r)
                    gates[r] = px[r]
                             + ((float)ahh[r] * 65536.f + (float)amid[r] * 256.f) * (1.f / 8589934592.f)
                             + offs[lane & 31];
            } else {
                // layer1: input h1 = h0(p-1), recurrent h2(p-2); both scale 2^33
#pragma unroll 4
                for (int s = 0; s < 32; ++s)
                    kstep(hprev + s * 32, wlds + s * 2048 + lane * 16, ahh, amid);
                const short* h2p = h2q + ((p + 1) & 1) * 65536 + mrow * 1024 + ksub;
#pragma unroll 4
                for (int s = 0; s < 32; ++s)
                    kstep(h2p + s * 32, wlds + (32 + s) * 2048 + lane * 16, ahh, amid);
#pragma unroll
                for (int r = 0; r < 16; ++r)
                    gates[r] = ((float)ahh[r] * 65536.f + (float)amid[r] * 256.f) * (1.f / 8589934592.f)
                             + offs[lane & 31];
            }
            // scatter C/D frag to LDS: col=lane&31, row=(r&3)+8*(r>>2)+4*(lane>>5)
            {
                const int rbase = (tid >> 6) * 32 + 4 * (lane >> 5);
                const int c = lane & 31;
#pragma unroll
                for (int r = 0; r < 16; ++r) {
                    int row = rbase + (r & 3) + 8 * (r >> 2);
                    gbuf[row * 33 + c] = gates[r];
                }
            }
        }
        __syncthreads();
        if (active) {
            // state update: 512 (row,unit) tasks over 128 threads
            short* hw = ((layer == 0) ? h0q : h2q) + (p & 1) * 65536;
#pragma unroll
            for (int q = 0; q < 4; ++q) {
                const int id = q * 128 + tid;
                const int r = id & 63;
                const int u = id >> 6;
                const float gi = gbuf[r * 33 + 4 * u + 0];
                const float gf = gbuf[r * 33 + 4 * u + 1];
                const float gg = gbuf[r * 33 + 4 * u + 2];
                const float go = gbuf[r * 33 + 4 * u + 3];
                const float i_ = 1.f / (1.f + __expf(-gi));
                const float f_ = 1.f / (1.f + __expf(-gf));
                const float g_ = 1.f - 2.f / (__expf(2.f * gg) + 1.f);
                const float o_ = 1.f / (1.f + __expf(-go));
                float c_ = f_ * cbuf[r * 9 + u] + i_ * g_;
                cbuf[r * 9 + u] = c_;
                const float h_ = o_ * (1.f - 2.f / (__expf(2.f * c_) + 1.f));
                const int jg = nblk * 8 + u;
                hw[r * 1024 + jg] = (short)__float2int_rn(h_ * 16384.f);  // scale 2^14
                if (layer == 1 && p == T_STEPS) h2f[r * 1024 + jg] = h_;
            }
        }
        __syncthreads();
        // -------- grid barrier (all 256 WGs co-resident by LDS exclusion) ----
        if (tid == 0) {
            __threadfence();
            unsigned old = atomicAdd(barcnt, 1u);
            if (old == (unsigned)(p * NWG + NWG - 1)) {
                atomicExch(bargen, (unsigned)(p + 1));
            } else {
                while (__hip_atomic_load(bargen, __ATOMIC_RELAXED, __HIP_MEMORY_SCOPE_AGENT)
                       < (unsigned)(p + 1)) {
                    __builtin_amdgcn_s_sleep(2);
                }
            }
            __threadfence();
        }
        __syncthreads();
        __threadfence();
    }
}

// ---------------------------------------------------------------------------
__global__ void final_lin(const float* __restrict__ h2f, const float* __restrict__ wlin,
                          const float* __restrict__ blin, float* __restrict__ out)
{
    const int b = blockIdx.x;
    const int l = threadIdx.x;
    float s = 0.f;
    for (int j = l; j < 1024; j += 64) s += h2f[b * 1024 + j] * wlin[j];
#pragma unroll
    for (int off = 32; off; off >>= 1) s += __shfl_down(s, off);
    if (l == 0) out[b] = s + blin[0];
}

// ---------------------------------------------------------------------------
extern "C" void kernel_launch(void* const* d_in, const int* in_sizes, int n_in,
                              void* d_out, int out_size, void* d_ws, size_t ws_size,
                              hipStream_t stream)
{
    const float* x    = (const float*)d_in[0];
    const float* wih0 = (const float*)d_in[1];
    const float* whh0 = (const float*)d_in[2];
    const float* bih0 = (const float*)d_in[3];
    const float* bhh0 = (const float*)d_in[4];
    const float* wih1 = (const float*)d_in[5];
    const float* whh1 = (const float*)d_in[6];
    const float* bih1 = (const float*)d_in[7];
    const float* bhh1 = (const float*)d_in[8];
    const float* wlin = (const float*)d_in[9];
    const float* blin = (const float*)d_in[10];

    // workspace layout
    char* ws = (char*)d_ws;
    unsigned* barcnt = (unsigned*)ws;                    // @0
    unsigned* bargen = (unsigned*)(ws + 64);             // @64
    short* h0q = (short*)(ws + 256);                     // [2][64][1024] i16 = 256KB
    short* h2q = (short*)(ws + 256 + 262144);            // 256KB
    float* h2f = (float*)(ws + 256 + 524288);            // [64][1024] f32 = 256KB
    short* xq  = (short*)(ws + 256 + 786432);            // [64][512][256] i16 = 16MB
    char*  wimg = ws + 256 + 786432 + 16777216;          // 256 * 128KB = 32MB

    // zero barrier + h ping-pong buffers (ws is poisoned 0xAA before each call)
    hipMemsetAsync(ws, 0, 256 + 524288, stream);

    quant_x<<<32768, 256, 0, stream>>>(x, xq, 64 * 512 * 256);
    quant_w<<<4096, 256, 0, stream>>>(wih0, whh0, wih1, whh1, wimg);

    static int smem_set = hipFuncSetAttribute((const void*)lstm_main,
        hipFuncAttributeMaxDynamicSharedMemorySize, SMEM_BYTES);
    (void)smem_set;
    hipFuncSetAttribute((const void*)lstm_main,
        hipFuncAttributeMaxDynamicSharedMemorySize, SMEM_BYTES);

    lstm_main<<<NWG, 128, SMEM_BYTES, stream>>>(xq, wimg, bih0, bhh0, bih1, bhh1,
                                                h0q, h2q, h2f, barcnt, bargen);
    final_lin<<<64, 64, 0, stream>>>(h2f, wlin, blin, (float*)d_out);
}

// Round 2
// 14099.469 us; speedup vs baseline: 1.6384x; 1.6384x over previous
//
#include <hip/hip_runtime.h>

// ============================================================================
// 2-layer LSTM (B=64,T=512,D=256,H=1024) + linear, fp32.
// Persistent-kernel, diagonal pipeline (phase p = L0 step p || L1 step p-1),
// int16 weights/activations split into two int8 planes, 3x i8-MFMA per K=32.
// R2: distributed grid barrier (per-WG arrival slots + master gather +
//     generation broadcast) replacing the contended single-counter atomicAdd
//     (R1 post-mortem: 256-way RMW on one line across 8 XCDs ~= 40us/phase).
// ============================================================================

#define T_STEPS 512
#define NWG 256
#define LDS_W     131072                  // [64 ksteps][2 planes][64 lanes][16B]
#define LDS_GBUF  (64 * 33 * 4)           // 8448, padded stride 33
#define LDS_CBUF  (64 * 9 * 4)            // 2304, padded stride 9
#define LDS_OFFS  (32 * 4)
#define SMEM_BYTES (LDS_W + LDS_GBUF + LDS_CBUF + LDS_OFFS)   // 141952

typedef int v4i  __attribute__((ext_vector_type(4)));
typedef int v16i __attribute__((ext_vector_type(16)));

__device__ __forceinline__ v16i zero16() {
    v16i z;
#pragma unroll
    for (int i = 0; i < 16; ++i) z[i] = 0;
    return z;
}

// One K=32 step: load 16 i16 activations (32B), split into hi/lo i8 planes,
// read B hi/lo frags from LDS, 3 int8 MFMAs.
__device__ __forceinline__ void kstep(const short* __restrict__ ap,
                                      const char* __restrict__ wl,
                                      v16i& ahh, v16i& amid)
{
    v4i A0 = *(const v4i*)ap;          // k0..k7  (8 x i16)
    v4i A1 = *(const v4i*)(ap + 8);    // k8..k15
    v4i HI, LO;
    HI.x = (int)__builtin_amdgcn_perm((unsigned)A0.y, (unsigned)A0.x, 0x07050301u);
    HI.y = (int)__builtin_amdgcn_perm((unsigned)A0.w, (unsigned)A0.z, 0x07050301u);
    HI.z = (int)__builtin_amdgcn_perm((unsigned)A1.y, (unsigned)A1.x, 0x07050301u);
    HI.w = (int)__builtin_amdgcn_perm((unsigned)A1.w, (unsigned)A1.z, 0x07050301u);
    // low byte, biased to signed: LO' = LO_u - 128  (bit pattern = byte ^ 0x80)
    LO.x = (int)(__builtin_amdgcn_perm((unsigned)A0.y, (unsigned)A0.x, 0x06040200u) ^ 0x80808080u);
    LO.y = (int)(__builtin_amdgcn_perm((unsigned)A0.w, (unsigned)A0.z, 0x06040200u) ^ 0x80808080u);
    LO.z = (int)(__builtin_amdgcn_perm((unsigned)A1.y, (unsigned)A1.x, 0x06040200u) ^ 0x80808080u);
    LO.w = (int)(__builtin_amdgcn_perm((unsigned)A1.w, (unsigned)A1.z, 0x06040200u) ^ 0x80808080u);
    v4i BH = *(const v4i*)wl;
    v4i BL = *(const v4i*)(wl + 1024);
    ahh  = __builtin_amdgcn_mfma_i32_32x32x32_i8(HI, BH, ahh, 0, 0, 0);
    amid = __builtin_amdgcn_mfma_i32_32x32x32_i8(HI, BL, amid, 0, 0, 0);
    amid = __builtin_amdgcn_mfma_i32_32x32x32_i8(LO, BH, amid, 0, 0, 0);
}

// ---------------------------------------------------------------------------
__global__ void quant_x(const float* __restrict__ x, short* __restrict__ xq, int n)
{
    int i = blockIdx.x * 256 + threadIdx.x;
    if (i < n) {
        float v = x[i] * 2048.f;
        v = fminf(fmaxf(v, -32767.f), 32767.f);
        xq[i] = (short)__float2int_rn(v);
    }
}

// prep: quantize + gate-reorder + fragment-tile weights into per-WG LDS images.
__global__ void quant_w(const float* __restrict__ wih0, const float* __restrict__ whh0,
                        const float* __restrict__ wih1, const float* __restrict__ whh1,
                        char* __restrict__ wimg)
{
    int gid = blockIdx.x * 256 + threadIdx.x;       // 256*64*64 = 1048576 threads
    if (gid >= 256 * 64 * 64) return;
    int lane = gid & 63;
    int s    = (gid >> 6) & 63;
    int wg   = gid >> 12;
    int layer = wg >> 7, nblk = wg & 127;
    int col = nblk * 32 + (lane & 31);
    int ro  = (col & 3) * 1024 + (col >> 2);        // original gate-blocked row
    int k0  = s * 32 + (lane >> 5) * 16;
    char* dst = wimg + (size_t)wg * LDS_W + s * 2048 + lane * 16;
#pragma unroll
    for (int j = 0; j < 16; ++j) {
        int k = k0 + j;
        float w = 0.f;
        if (layer == 0) {
            if (k < 256)       w = wih0[ro * 256 + k];
            else if (k < 1280) w = whh0[ro * 1024 + (k - 256)];
        } else {
            if (k < 1024)      w = wih1[ro * 1024 + k];
            else               w = whh1[ro * 1024 + (k - 1024)];
        }
        int q  = __float2int_rn(w * 524288.f);      // 2^19, |q|<=16384
        int hi = (q + 128) >> 8;
        int lo = q - (hi << 8);
        dst[j]        = (char)hi;
        dst[1024 + j] = (char)lo;
    }
}

// ---------------------------------------------------------------------------
__global__ void __launch_bounds__(128) lstm_main(
    const short* __restrict__ xq, const char* __restrict__ wimg,
    const float* __restrict__ bih0, const float* __restrict__ bhh0,
    const float* __restrict__ bih1, const float* __restrict__ bhh1,
    short* __restrict__ h0q, short* __restrict__ h2q,
    float* __restrict__ h2f, unsigned* slots, unsigned* bargen)
{
    extern __shared__ char smem[];
    char*  wlds = smem;
    float* gbuf = (float*)(smem + LDS_W);                       // [64][33]
    float* cbuf = (float*)(smem + LDS_W + LDS_GBUF);            // [64][9]
    float* offs = (float*)(smem + LDS_W + LDS_GBUF + LDS_CBUF); // [32]

    const int wg    = blockIdx.x;
    const int layer = wg >> 7;
    const int nblk  = wg & 127;
    const int tid   = threadIdx.x;
    const int lane  = tid & 63;

    // stage this WG's weight image into LDS (128KB)
    {
        const v4i* src = (const v4i*)(wimg + (size_t)wg * LDS_W);
        v4i* dst = (v4i*)wlds;
        for (int i = tid; i < LDS_W / 16; i += 128) dst[i] = src[i];
    }
    for (int i = tid; i < 64 * 9; i += 128) cbuf[i] = 0.f;
    __syncthreads();

    // per-col constant: 128*colsum16*inv_scale (LO'=-128 bias comp) + gate bias
    if (tid < 32) {
        const int c  = tid;
        const int ns = (layer == 0) ? 40 : 64;
        int cs_x = 0, cs_h = 0;
        for (int s = 0; s < ns; ++s) {
            int sum = 0;
#pragma unroll
            for (int half = 0; half < 2; ++half) {
                const signed char* ph = (const signed char*)(wlds + s * 2048 + (half * 32 + c) * 16);
#pragma unroll
                for (int j = 0; j < 16; ++j)
                    sum += 256 * (int)ph[j] + (int)ph[1024 + j];
            }
            if (layer == 0 && s < 8) cs_x += sum; else cs_h += sum;
        }
        const int col = nblk * 32 + c;
        const int ro  = (col & 3) * 1024 + (col >> 2);
        const float bias = (layer == 0) ? (bih0[ro] + bhh0[ro]) : (bih1[ro] + bhh1[ro]);
        float off = 128.f * (float)cs_h * (1.f / 8589934592.f) + bias;   // /2^33
        if (layer == 0) off += 128.f * (float)cs_x * (1.f / 1073741824.f); // /2^30
        offs[c] = off;
    }
    __syncthreads();

    const int mrow = (tid >> 6) * 32 + (lane & 31);   // batch row of A fragment
    const int ksub = (lane >> 5) * 16;                // k sub-offset (i16 units)
    unsigned* myslot = slots + wg * 16;               // 64B-padded arrival slot

    for (int p = 0; p <= T_STEPS; ++p) {
        const bool active = (layer == 0) ? (p < T_STEPS) : (p >= 1);
        if (active) {
            const short* hprev = h0q + ((p + 1) & 1) * 65536 + mrow * 1024 + ksub; // h0(p-1)
            float gates[16];
            v16i ahh = zero16(), amid = zero16();
            if (layer == 0) {
                // x segment (K=256, scale 2^11 * 2^19 = 2^30)
                const short* ax = xq + ((size_t)mrow * 512 + p) * 256 + ksub;
#pragma unroll
                for (int s = 0; s < 8; ++s)
                    kstep(ax + s * 32, wlds + s * 2048 + lane * 16, ahh, amid);
                float px[16];
#pragma unroll
                for (int r = 0; r < 16; ++r)
                    px[r] = ((float)ahh[r] * 65536.f + (float)amid[r] * 256.f) * (1.f / 1073741824.f);
                ahh = zero16(); amid = zero16();
                // h segment (K=1024, scale 2^14 * 2^19 = 2^33)
#pragma unroll 8
                for (int s = 0; s < 32; ++s)
                    kstep(hprev + s * 32, wlds + (8 + s) * 2048 + lane * 16, ahh, amid);
#pragma unroll
                for (int r = 0; r < 16; ++r)
                    gates[r] = px[r]
                             + ((float)ahh[r] * 65536.f + (float)amid[r] * 256.f) * (1.f / 8589934592.f)
                             + offs[lane & 31];
            } else {
                // layer1: input h1 = h0(p-1), recurrent h2(p-2); both scale 2^33
#pragma unroll 8
                for (int s = 0; s < 32; ++s)
                    kstep(hprev + s * 32, wlds + s * 2048 + lane * 16, ahh, amid);
                const short* h2p = h2q + ((p + 1) & 1) * 65536 + mrow * 1024 + ksub;
#pragma unroll 8
                for (int s = 0; s < 32; ++s)
                    kstep(h2p + s * 32, wlds + (32 + s) * 2048 + lane * 16, ahh, amid);
#pragma unroll
                for (int r = 0; r < 16; ++r)
                    gates[r] = ((float)ahh[r] * 65536.f + (float)amid[r] * 256.f) * (1.f / 8589934592.f)
                             + offs[lane & 31];
            }
            // scatter C/D frag to LDS: col=lane&31, row=(r&3)+8*(r>>2)+4*(lane>>5)
            {
                const int rbase = (tid >> 6) * 32 + 4 * (lane >> 5);
                const int c = lane & 31;
#pragma unroll
                for (int r = 0; r < 16; ++r) {
                    int row = rbase + (r & 3) + 8 * (r >> 2);
                    gbuf[row * 33 + c] = gates[r];
                }
            }
        }
        __syncthreads();
        if (active) {
            // state update: 512 (row,unit) tasks over 128 threads
            short* hw = ((layer == 0) ? h0q : h2q) + (p & 1) * 65536;
#pragma unroll
            for (int q = 0; q < 4; ++q) {
                const int id = q * 128 + tid;
                const int r = id & 63;
                const int u = id >> 6;
                const float gi = gbuf[r * 33 + 4 * u + 0];
                const float gf = gbuf[r * 33 + 4 * u + 1];
                const float gg = gbuf[r * 33 + 4 * u + 2];
                const float go = gbuf[r * 33 + 4 * u + 3];
                const float i_ = 1.f / (1.f + __expf(-gi));
                const float f_ = 1.f / (1.f + __expf(-gf));
                const float g_ = 1.f - 2.f / (__expf(2.f * gg) + 1.f);
                const float o_ = 1.f / (1.f + __expf(-go));
                float c_ = f_ * cbuf[r * 9 + u] + i_ * g_;
                cbuf[r * 9 + u] = c_;
                const float h_ = o_ * (1.f - 2.f / (__expf(2.f * c_) + 1.f));
                const int jg = nblk * 8 + u;
                hw[r * 1024 + jg] = (short)__float2int_rn(h_ * 16384.f);  // scale 2^14
                if (layer == 1 && p == T_STEPS) h2f[r * 1024 + jg] = h_;
            }
        }
        __syncthreads();
        // -------- distributed grid barrier --------------------------------
        // Arrival: each WG release-stores (p+1) to its own 64B slot.
        // Gather: WG0's 128 threads poll 2 slots each (parallel, read-only).
        // Broadcast: WG0 stores generation; others read-share-poll it.
        {
            const unsigned p1 = (unsigned)(p + 1);
            if (tid == 0) {
                __threadfence();
                __hip_atomic_store(myslot, p1, __ATOMIC_RELAXED, __HIP_MEMORY_SCOPE_AGENT);
            }
            if (wg == 0) {
                unsigned* s0 = slots + (tid * 2) * 16;
                unsigned* s1 = slots + (tid * 2 + 1) * 16;
                while (__hip_atomic_load(s0, __ATOMIC_RELAXED, __HIP_MEMORY_SCOPE_AGENT) < p1)
                    __builtin_amdgcn_s_sleep(1);
                while (__hip_atomic_load(s1, __ATOMIC_RELAXED, __HIP_MEMORY_SCOPE_AGENT) < p1)
                    __builtin_amdgcn_s_sleep(1);
                __syncthreads();
                if (tid == 0) {
                    __threadfence();
                    __hip_atomic_store(bargen, p1, __ATOMIC_RELAXED, __HIP_MEMORY_SCOPE_AGENT);
                }
            } else {
                if (tid == 0) {
                    while (__hip_atomic_load(bargen, __ATOMIC_RELAXED, __HIP_MEMORY_SCOPE_AGENT) < p1)
                        __builtin_amdgcn_s_sleep(4);
                    __threadfence();
                }
            }
            __syncthreads();
        }
    }
}

// ---------------------------------------------------------------------------
__global__ void final_lin(const float* __restrict__ h2f, const float* __restrict__ wlin,
                          const float* __restrict__ blin, float* __restrict__ out)
{
    const int b = blockIdx.x;
    const int l = threadIdx.x;
    float s = 0.f;
    for (int j = l; j < 1024; j += 64) s += h2f[b * 1024 + j] * wlin[j];
#pragma unroll
    for (int off = 32; off; off >>= 1) s += __shfl_down(s, off);
    if (l == 0) out[b] = s + blin[0];
}

// ---------------------------------------------------------------------------
extern "C" void kernel_launch(void* const* d_in, const int* in_sizes, int n_in,
                              void* d_out, int out_size, void* d_ws, size_t ws_size,
                              hipStream_t stream)
{
    const float* x    = (const float*)d_in[0];
    const float* wih0 = (const float*)d_in[1];
    const float* whh0 = (const float*)d_in[2];
    const float* bih0 = (const float*)d_in[3];
    const float* bhh0 = (const float*)d_in[4];
    const float* wih1 = (const float*)d_in[5];
    const float* whh1 = (const float*)d_in[6];
    const float* bih1 = (const float*)d_in[7];
    const float* bhh1 = (const float*)d_in[8];
    const float* wlin = (const float*)d_in[9];
    const float* blin = (const float*)d_in[10];

    // workspace layout
    char* ws = (char*)d_ws;
    unsigned* bargen = (unsigned*)ws;                    // @0
    unsigned* slots  = (unsigned*)(ws + 256);            // 256 x 64B = 16KB
    short* h0q = (short*)(ws + 32768);                   // [2][64][1024] i16 = 256KB
    short* h2q = (short*)(ws + 32768 + 262144);          // 256KB
    float* h2f = (float*)(ws + 32768 + 524288);          // [64][1024] f32 = 256KB
    short* xq  = (short*)(ws + 32768 + 786432);          // [64][512][256] i16 = 16MB
    char*  wimg = ws + 32768 + 786432 + 16777216;        // 256 * 128KB = 32MB

    // zero barrier state + h ping-pong buffers (ws re-poisoned 0xAA each call)
    hipMemsetAsync(ws, 0, 32768 + 524288, stream);

    quant_x<<<32768, 256, 0, stream>>>(x, xq, 64 * 512 * 256);
    quant_w<<<4096, 256, 0, stream>>>(wih0, whh0, wih1, whh1, wimg);

    hipFuncSetAttribute((const void*)lstm_main,
        hipFuncAttributeMaxDynamicSharedMemorySize, SMEM_BYTES);

    lstm_main<<<NWG, 128, SMEM_BYTES, stream>>>(xq, wimg, bih0, bhh0, bih1, bhh1,
                                                h0q, h2q, h2f, slots, bargen);
    final_lin<<<64, 64, 0, stream>>>(h2f, wlin, blin, (float*)d_out);
}

// Round 3
// 7407.423 us; speedup vs baseline: 3.1186x; 1.9034x over previous
//
#include <hip/hip_runtime.h>

// ============================================================================
// 2-layer LSTM (B=64,T=512,D=256,H=1024) + linear, fp32.
// Persistent kernel, diagonal pipeline (phase p = L0 step p || L1 step p-1),
// int16 weights/acts split into two int8 planes, 3x i8-MFMA per K=32.
// R3: remove per-phase cache-maintenance fences (R2 post-mortem: threadfence
//     acquire = full L1+L2 inv, release = wbl2, per WG per phase ~= 25us).
//     h ping-pong traffic now bypasses L1/L2 (sc0 sc1 -> MALL = coherence
//     point): stores write-through + vmcnt(0); loads are 16-deep batched
//     asm global_load_dwordx4 sc0 sc1. Per-WG 64B broadcast slots kill the
//     single-line poll contention.
// ============================================================================

#define T_STEPS 512
#define NWG 256
#define LDS_W     131072                  // [64 ksteps][2 planes][64 lanes][16B]
#define LDS_GBUF  (64 * 33 * 4)           // 8448, padded stride 33
#define LDS_CBUF  (64 * 9 * 4)            // 2304, padded stride 9
#define LDS_OFFS  (32 * 4)
#define SMEM_BYTES (LDS_W + LDS_GBUF + LDS_CBUF + LDS_OFFS)   // 141952

typedef int v2i  __attribute__((ext_vector_type(2)));
typedef int v4i  __attribute__((ext_vector_type(4)));
typedef int v16i __attribute__((ext_vector_type(16)));

__device__ __forceinline__ v16i zero16() {
    v16i z;
#pragma unroll
    for (int i = 0; i < 16; ++i) z[i] = 0;
    return z;
}

// 16x global_load_dwordx4 sc0 sc1 (MALL-direct, bypass L1/L2) + one waitcnt.
// Covers 8 ksteps (per lane: 8 x 32B at 64B stride, A0 at +64j, A1 at +64j+16).
__device__ __forceinline__ void load_h16(const short* base, v4i* o) {
    asm volatile(
        "global_load_dwordx4 %0, %16, off sc0 sc1\n\t"
        "global_load_dwordx4 %1, %16, off offset:16 sc0 sc1\n\t"
        "global_load_dwordx4 %2, %16, off offset:64 sc0 sc1\n\t"
        "global_load_dwordx4 %3, %16, off offset:80 sc0 sc1\n\t"
        "global_load_dwordx4 %4, %16, off offset:128 sc0 sc1\n\t"
        "global_load_dwordx4 %5, %16, off offset:144 sc0 sc1\n\t"
        "global_load_dwordx4 %6, %16, off offset:192 sc0 sc1\n\t"
        "global_load_dwordx4 %7, %16, off offset:208 sc0 sc1\n\t"
        "global_load_dwordx4 %8, %16, off offset:256 sc0 sc1\n\t"
        "global_load_dwordx4 %9, %16, off offset:272 sc0 sc1\n\t"
        "global_load_dwordx4 %10, %16, off offset:320 sc0 sc1\n\t"
        "global_load_dwordx4 %11, %16, off offset:336 sc0 sc1\n\t"
        "global_load_dwordx4 %12, %16, off offset:384 sc0 sc1\n\t"
        "global_load_dwordx4 %13, %16, off offset:400 sc0 sc1\n\t"
        "global_load_dwordx4 %14, %16, off offset:448 sc0 sc1\n\t"
        "global_load_dwordx4 %15, %16, off offset:464 sc0 sc1\n\t"
        "s_waitcnt vmcnt(0)"
        : "=&v"(o[0]), "=&v"(o[1]), "=&v"(o[2]), "=&v"(o[3]),
          "=&v"(o[4]), "=&v"(o[5]), "=&v"(o[6]), "=&v"(o[7]),
          "=&v"(o[8]), "=&v"(o[9]), "=&v"(o[10]), "=&v"(o[11]),
          "=&v"(o[12]), "=&v"(o[13]), "=&v"(o[14]), "=&v"(o[15])
        : "v"(base)
        : "memory");
}

__device__ __forceinline__ void store_h8(short* p, v2i v) {
    asm volatile("global_store_dwordx2 %0, %1, off sc0 sc1"
                 :: "v"(p), "v"(v) : "memory");
}

__device__ __forceinline__ void waitcnt0() {
    asm volatile("s_waitcnt vmcnt(0)" ::: "memory");
}

// Split 16 i16 into hi/lo i8 planes + 3 int8 MFMAs (register-input variant).
__device__ __forceinline__ void kstep_r(v4i A0, v4i A1,
                                        const char* __restrict__ wl,
                                        v16i& ahh, v16i& amid)
{
    v4i HI, LO;
    HI.x = (int)__builtin_amdgcn_perm((unsigned)A0.y, (unsigned)A0.x, 0x07050301u);
    HI.y = (int)__builtin_amdgcn_perm((unsigned)A0.w, (unsigned)A0.z, 0x07050301u);
    HI.z = (int)__builtin_amdgcn_perm((unsigned)A1.y, (unsigned)A1.x, 0x07050301u);
    HI.w = (int)__builtin_amdgcn_perm((unsigned)A1.w, (unsigned)A1.z, 0x07050301u);
    LO.x = (int)(__builtin_amdgcn_perm((unsigned)A0.y, (unsigned)A0.x, 0x06040200u) ^ 0x80808080u);
    LO.y = (int)(__builtin_amdgcn_perm((unsigned)A0.w, (unsigned)A0.z, 0x06040200u) ^ 0x80808080u);
    LO.z = (int)(__builtin_amdgcn_perm((unsigned)A1.y, (unsigned)A1.x, 0x06040200u) ^ 0x80808080u);
    LO.w = (int)(__builtin_amdgcn_perm((unsigned)A1.w, (unsigned)A1.z, 0x06040200u) ^ 0x80808080u);
    v4i BH = *(const v4i*)wl;
    v4i BL = *(const v4i*)(wl + 1024);
    ahh  = __builtin_amdgcn_mfma_i32_32x32x32_i8(HI, BH, ahh, 0, 0, 0);
    amid = __builtin_amdgcn_mfma_i32_32x32x32_i8(HI, BL, amid, 0, 0, 0);
    amid = __builtin_amdgcn_mfma_i32_32x32x32_i8(LO, BH, amid, 0, 0, 0);
}

// pointer-load variant (cached; used for the read-only x segment)
__device__ __forceinline__ void kstep(const short* __restrict__ ap,
                                      const char* __restrict__ wl,
                                      v16i& ahh, v16i& amid)
{
    v4i A0 = *(const v4i*)ap;
    v4i A1 = *(const v4i*)(ap + 8);
    kstep_r(A0, A1, wl, ahh, amid);
}

// ---------------------------------------------------------------------------
__global__ void quant_x(const float* __restrict__ x, short* __restrict__ xq, int n)
{
    int i = blockIdx.x * 256 + threadIdx.x;
    if (i < n) {
        float v = x[i] * 2048.f;
        v = fminf(fmaxf(v, -32767.f), 32767.f);
        xq[i] = (short)__float2int_rn(v);
    }
}

// prep: quantize + gate-reorder + fragment-tile weights into per-WG LDS images.
__global__ void quant_w(const float* __restrict__ wih0, const float* __restrict__ whh0,
                        const float* __restrict__ wih1, const float* __restrict__ whh1,
                        char* __restrict__ wimg)
{
    int gid = blockIdx.x * 256 + threadIdx.x;       // 256*64*64 = 1048576 threads
    if (gid >= 256 * 64 * 64) return;
    int lane = gid & 63;
    int s    = (gid >> 6) & 63;
    int wg   = gid >> 12;
    int layer = wg >> 7, nblk = wg & 127;
    int col = nblk * 32 + (lane & 31);
    int ro  = (col & 3) * 1024 + (col >> 2);        // original gate-blocked row
    int k0  = s * 32 + (lane >> 5) * 16;
    char* dst = wimg + (size_t)wg * LDS_W + s * 2048 + lane * 16;
#pragma unroll
    for (int j = 0; j < 16; ++j) {
        int k = k0 + j;
        float w = 0.f;
        if (layer == 0) {
            if (k < 256)       w = wih0[ro * 256 + k];
            else if (k < 1280) w = whh0[ro * 1024 + (k - 256)];
        } else {
            if (k < 1024)      w = wih1[ro * 1024 + k];
            else               w = whh1[ro * 1024 + (k - 1024)];
        }
        int q  = __float2int_rn(w * 524288.f);      // 2^19, |q|<=16384
        int hi = (q + 128) >> 8;
        int lo = q - (hi << 8);
        dst[j]        = (char)hi;
        dst[1024 + j] = (char)lo;
    }
}

// ---------------------------------------------------------------------------
__global__ void __launch_bounds__(128) lstm_main(
    const short* __restrict__ xq, const char* __restrict__ wimg,
    const float* __restrict__ bih0, const float* __restrict__ bhh0,
    const float* __restrict__ bih1, const float* __restrict__ bhh1,
    short* __restrict__ h0q, short* __restrict__ h2q,
    float* __restrict__ h2f, unsigned* slots, unsigned* bcast)
{
    extern __shared__ char smem[];
    char*  wlds = smem;
    float* gbuf = (float*)(smem + LDS_W);                       // [64][33]
    float* cbuf = (float*)(smem + LDS_W + LDS_GBUF);            // [64][9]
    float* offs = (float*)(smem + LDS_W + LDS_GBUF + LDS_CBUF); // [32]

    const int wg    = blockIdx.x;
    const int layer = wg >> 7;
    const int nblk  = wg & 127;
    const int tid   = threadIdx.x;
    const int lane  = tid & 63;

    // stage this WG's weight image into LDS (128KB)
    {
        const v4i* src = (const v4i*)(wimg + (size_t)wg * LDS_W);
        v4i* dst = (v4i*)wlds;
        for (int i = tid; i < LDS_W / 16; i += 128) dst[i] = src[i];
    }
    for (int i = tid; i < 64 * 9; i += 128) cbuf[i] = 0.f;
    __syncthreads();

    // per-col constant: 128*colsum16*inv_scale (LO'=-128 bias comp) + gate bias
    if (tid < 32) {
        const int c  = tid;
        const int ns = (layer == 0) ? 40 : 64;
        int cs_x = 0, cs_h = 0;
        for (int s = 0; s < ns; ++s) {
            int sum = 0;
#pragma unroll
            for (int half = 0; half < 2; ++half) {
                const signed char* ph = (const signed char*)(wlds + s * 2048 + (half * 32 + c) * 16);
#pragma unroll
                for (int j = 0; j < 16; ++j)
                    sum += 256 * (int)ph[j] + (int)ph[1024 + j];
            }
            if (layer == 0 && s < 8) cs_x += sum; else cs_h += sum;
        }
        const int col = nblk * 32 + c;
        const int ro  = (col & 3) * 1024 + (col >> 2);
        const float bias = (layer == 0) ? (bih0[ro] + bhh0[ro]) : (bih1[ro] + bhh1[ro]);
        float off = 128.f * (float)cs_h * (1.f / 8589934592.f) + bias;   // /2^33
        if (layer == 0) off += 128.f * (float)cs_x * (1.f / 1073741824.f); // /2^30
        offs[c] = off;
    }
    __syncthreads();

    const int mrow = (tid >> 6) * 32 + (lane & 31);   // batch row of A fragment
    const int ksub = (lane >> 5) * 16;                // k sub-offset (i16 units)

    for (int p = 0; p <= T_STEPS; ++p) {
        const bool active = (layer == 0) ? (p < T_STEPS) : (p >= 1);
        if (active) {
            const short* hprev = h0q + ((p + 1) & 1) * 65536 + mrow * 1024 + ksub; // h0(p-1)
            float gates[16];
            v16i ahh = zero16(), amid = zero16();
            v4i hb[16];
            if (layer == 0) {
                // x segment (K=256, cached loads; scale 2^11 * 2^19 = 2^30)
                const short* ax = xq + ((size_t)mrow * 512 + p) * 256 + ksub;
#pragma unroll
                for (int s = 0; s < 8; ++s)
                    kstep(ax + s * 32, wlds + s * 2048 + lane * 16, ahh, amid);
                float px[16];
#pragma unroll
                for (int r = 0; r < 16; ++r)
                    px[r] = ((float)ahh[r] * 65536.f + (float)amid[r] * 256.f) * (1.f / 1073741824.f);
                ahh = zero16(); amid = zero16();
                // h segment (K=1024, MALL-direct; scale 2^14 * 2^19 = 2^33)
                for (int c = 0; c < 4; ++c) {
                    load_h16(hprev + c * 256, hb);
#pragma unroll
                    for (int s = 0; s < 8; ++s)
                        kstep_r(hb[2 * s], hb[2 * s + 1],
                                wlds + (8 + c * 8 + s) * 2048 + lane * 16, ahh, amid);
                }
#pragma unroll
                for (int r = 0; r < 16; ++r)
                    gates[r] = px[r]
                             + ((float)ahh[r] * 65536.f + (float)amid[r] * 256.f) * (1.f / 8589934592.f)
                             + offs[lane & 31];
            } else {
                // layer1: input h1 = h0(p-1), recurrent h2(p-2); both scale 2^33
                for (int c = 0; c < 4; ++c) {
                    load_h16(hprev + c * 256, hb);
#pragma unroll
                    for (int s = 0; s < 8; ++s)
                        kstep_r(hb[2 * s], hb[2 * s + 1],
                                wlds + (c * 8 + s) * 2048 + lane * 16, ahh, amid);
                }
                const short* h2p = h2q + ((p + 1) & 1) * 65536 + mrow * 1024 + ksub;
                for (int c = 0; c < 4; ++c) {
                    load_h16(h2p + c * 256, hb);
#pragma unroll
                    for (int s = 0; s < 8; ++s)
                        kstep_r(hb[2 * s], hb[2 * s + 1],
                                wlds + (32 + c * 8 + s) * 2048 + lane * 16, ahh, amid);
                }
#pragma unroll
                for (int r = 0; r < 16; ++r)
                    gates[r] = ((float)ahh[r] * 65536.f + (float)amid[r] * 256.f) * (1.f / 8589934592.f)
                             + offs[lane & 31];
            }
            // scatter C/D frag to LDS: col=lane&31, row=(r&3)+8*(r>>2)+4*(lane>>5)
            {
                const int rbase = (tid >> 6) * 32 + 4 * (lane >> 5);
                const int c = lane & 31;
#pragma unroll
                for (int r = 0; r < 16; ++r) {
                    int row = rbase + (r & 3) + 8 * (r >> 2);
                    gbuf[row * 33 + c] = gates[r];
                }
            }
        }
        __syncthreads();
        if (active) {
            // state update: thread = (row r, unit quad half*4..half*4+3),
            // one 8B MALL-direct store per thread.
            short* hw = ((layer == 0) ? h0q : h2q) + (p & 1) * 65536;
            const int r    = tid & 63;
            const int half = tid >> 6;
            unsigned hq[4];
            float hf[4];
#pragma unroll
            for (int j = 0; j < 4; ++j) {
                const int u = half * 4 + j;
                const float gi = gbuf[r * 33 + 4 * u + 0];
                const float gf = gbuf[r * 33 + 4 * u + 1];
                const float gg = gbuf[r * 33 + 4 * u + 2];
                const float go = gbuf[r * 33 + 4 * u + 3];
                const float i_ = 1.f / (1.f + __expf(-gi));
                const float f_ = 1.f / (1.f + __expf(-gf));
                const float g_ = 1.f - 2.f / (__expf(2.f * gg) + 1.f);
                const float o_ = 1.f / (1.f + __expf(-go));
                float c_ = f_ * cbuf[r * 9 + u] + i_ * g_;
                cbuf[r * 9 + u] = c_;
                const float h_ = o_ * (1.f - 2.f / (__expf(2.f * c_) + 1.f));
                hq[j] = (unsigned)(unsigned short)(short)__float2int_rn(h_ * 16384.f);
                hf[j] = h_;
            }
            v2i pk;
            pk.x = (int)(hq[0] | (hq[1] << 16));
            pk.y = (int)(hq[2] | (hq[3] << 16));
            const int jg = nblk * 8 + half * 4;
            store_h8(hw + r * 1024 + jg, pk);
            if (layer == 1 && p == T_STEPS) {
#pragma unroll
                for (int j = 0; j < 4; ++j) h2f[r * 1024 + jg + j] = hf[j];
            }
        }
        // -------- grid barrier: no cache-maintenance fences ----------------
        {
            const unsigned p1 = (unsigned)(p + 1);
            waitcnt0();            // all waves: own MALL stores complete
            __syncthreads();       // both waves' stores complete before signal
            if (tid == 0)
                __hip_atomic_store(slots + wg * 16, p1,
                                   __ATOMIC_RELAXED, __HIP_MEMORY_SCOPE_AGENT);
            if (wg == 0) {
                unsigned* s0 = slots + (tid * 2) * 16;
                unsigned* s1 = slots + (tid * 2 + 1) * 16;
                while (__hip_atomic_load(s0, __ATOMIC_RELAXED, __HIP_MEMORY_SCOPE_AGENT) < p1)
                    __builtin_amdgcn_s_sleep(1);
                while (__hip_atomic_load(s1, __ATOMIC_RELAXED, __HIP_MEMORY_SCOPE_AGENT) < p1)
                    __builtin_amdgcn_s_sleep(1);
                __syncthreads();
                __hip_atomic_store(bcast + (tid * 2) * 16, p1,
                                   __ATOMIC_RELAXED, __HIP_MEMORY_SCOPE_AGENT);
                __hip_atomic_store(bcast + (tid * 2 + 1) * 16, p1,
                                   __ATOMIC_RELAXED, __HIP_MEMORY_SCOPE_AGENT);
            } else if (tid == 0) {
                while (__hip_atomic_load(bcast + wg * 16, __ATOMIC_RELAXED, __HIP_MEMORY_SCOPE_AGENT) < p1)
                    __builtin_amdgcn_s_sleep(1);
            }
            __syncthreads();
        }
    }
}

// ---------------------------------------------------------------------------
__global__ void final_lin(const float* __restrict__ h2f, const float* __restrict__ wlin,
                          const float* __restrict__ blin, float* __restrict__ out)
{
    const int b = blockIdx.x;
    const int l = threadIdx.x;
    float s = 0.f;
    for (int j = l; j < 1024; j += 64) s += h2f[b * 1024 + j] * wlin[j];
#pragma unroll
    for (int off = 32; off; off >>= 1) s += __shfl_down(s, off);
    if (l == 0) out[b] = s + blin[0];
}

// ---------------------------------------------------------------------------
extern "C" void kernel_launch(void* const* d_in, const int* in_sizes, int n_in,
                              void* d_out, int out_size, void* d_ws, size_t ws_size,
                              hipStream_t stream)
{
    const float* x    = (const float*)d_in[0];
    const float* wih0 = (const float*)d_in[1];
    const float* whh0 = (const float*)d_in[2];
    const float* bih0 = (const float*)d_in[3];
    const float* bhh0 = (const float*)d_in[4];
    const float* wih1 = (const float*)d_in[5];
    const float* whh1 = (const float*)d_in[6];
    const float* bih1 = (const float*)d_in[7];
    const float* bhh1 = (const float*)d_in[8];
    const float* wlin = (const float*)d_in[9];
    const float* blin = (const float*)d_in[10];

    // workspace layout
    char* ws = (char*)d_ws;
    unsigned* slots = (unsigned*)ws;                     // 256 x 64B = 16KB
    unsigned* bcast = (unsigned*)(ws + 16384);           // 256 x 64B = 16KB
    short* h0q = (short*)(ws + 65536);                   // [2][64][1024] i16 = 256KB
    short* h2q = (short*)(ws + 65536 + 262144);          // 256KB
    float* h2f = (float*)(ws + 65536 + 524288);          // [64][1024] f32 = 256KB
    short* xq  = (short*)(ws + 65536 + 786432);          // [64][512][256] i16 = 16MB
    char*  wimg = ws + 65536 + 786432 + 16777216;        // 256 * 128KB = 32MB

    // zero barrier state + h ping-pong buffers (ws re-poisoned 0xAA each call)
    hipMemsetAsync(ws, 0, 65536 + 524288, stream);

    quant_x<<<32768, 256, 0, stream>>>(x, xq, 64 * 512 * 256);
    quant_w<<<4096, 256, 0, stream>>>(wih0, whh0, wih1, whh1, wimg);

    hipFuncSetAttribute((const void*)lstm_main,
        hipFuncAttributeMaxDynamicSharedMemorySize, SMEM_BYTES);

    lstm_main<<<NWG, 128, SMEM_BYTES, stream>>>(xq, wimg, bih0, bhh0, bih1, bhh1,
                                                h0q, h2q, h2f, slots, bcast);
    final_lin<<<64, 64, 0, stream>>>(h2f, wlin, blin, (float*)d_out);
}